// Round 13
// baseline (335.395 us; speedup 1.0000x reference)
//
#include <hip/hip_runtime.h>
#include <stdint.h>
#include <math.h>

#define D_MODEL 1024
#define D_INNER 2048
#define N_RES   1024
#define SEQ     4096
#define BATCH   4
#define M_TOT   (BATCH*SEQ)   // 16384
#define SMEM_BYTES 131072

typedef float f32x4 __attribute__((ext_vector_type(4)));
typedef float f32x16 __attribute__((ext_vector_type(16)));
typedef short bf16x8 __attribute__((ext_vector_type(8)));
typedef int   i32x4v __attribute__((ext_vector_type(4)));
typedef int   i32x8  __attribute__((ext_vector_type(8)));
typedef unsigned short u16;
typedef unsigned char u8;

__device__ __forceinline__ u16 f2bf(float f) {
  uint32_t u = __builtin_bit_cast(uint32_t, f);
  u += 0x7FFFu + ((u >> 16) & 1u);   // RNE
  return (u16)(u >> 16);
}
__device__ __forceinline__ float bf2f(u16 h) {
  return __builtin_bit_cast(float, (uint32_t)h << 16);
}

// ---- fp8 e4m3fn (OCP) encode/decode; builtin ICE operands via template ----
__device__ __forceinline__ uint32_t enc1_e4m3(float f) {
  uint32_t b = __builtin_bit_cast(uint32_t, f);
  uint32_t s = (b >> 24) & 0x80u;
  uint32_t a = b & 0x7FFFFFFFu;
  if (a >= 0x43E00000u) return s | 0x7Eu;            // >=448 or NaN -> sat
  if (a < 0x3C800000u) {                             // < 2^-6 -> subnormal
    float q = __builtin_bit_cast(float, a) * 512.f;
    uint32_t m = (uint32_t)(q + 0.5f);
    return s | (m > 7u ? 8u : m);
  }
  uint32_t lsb = (a >> 20) & 1u;
  a += 0x0007FFFFu + lsb;                            // RNE at mantissa bit 20
  uint32_t e8 = (a >> 23) - 120u;
  if (e8 >= 16u) return s | 0x7Eu;
  return s | (e8 << 3) | ((a >> 20) & 7u);
}
__device__ __forceinline__ float dec1_e4m3(uint32_t v) {
  uint32_t e = (v >> 3) & 15u, m = v & 7u;
  float mag = e ? __builtin_bit_cast(float, ((e + 120u) << 23) | (m << 20))
                : (float)m * 0.001953125f;
  return (v & 0x80u) ? -mag : mag;
}
template<bool HI>
__device__ __forceinline__ int pk_fp8(float a, float b, int old) {
#if __has_builtin(__builtin_amdgcn_cvt_pk_fp8_f32)
  return __builtin_amdgcn_cvt_pk_fp8_f32(a, b, old, HI);
#else
  uint32_t w = enc1_e4m3(a) | (enc1_e4m3(b) << 8);
  return HI ? (int)(((uint32_t)old & 0xFFFFu) | (w << 16))
            : (int)(((uint32_t)old & 0xFFFF0000u) | w);
#endif
}
template<int SEL>
__device__ __forceinline__ float up_fp8(int w) {
#if __has_builtin(__builtin_amdgcn_cvt_f32_fp8)
  return __builtin_amdgcn_cvt_f32_fp8(w, SEL);
#else
  return dec1_e4m3(((uint32_t)w >> (SEL * 8)) & 0xFFu);
#endif
}

__device__ __forceinline__ void g2l16(const void* g, void* l) {
  __builtin_amdgcn_global_load_lds(
      (const __attribute__((address_space(1))) void*)g,
      (__attribute__((address_space(3))) void*)l, 16, 0, 0);
}

// ---------------- fused convert (1 launch) ----------------------------------
// x -> bf16 AND fp8*16 ; w1 rows 0..2047 -> fp8*16, rows 2048..3071 -> bf16 ;
// w2,w3 -> fp8*16.
#define CVT_N0 4194304   // x   : 16384*1024/4
#define CVT_N1  524288   // w1u : 2048*1024/4
#define CVT_N2  262144   // w1r : 1024*1024/4
#define CVT_N3 1048576   // w2  : 2048*2048/4
#define CVT_N4  524288   // w3  : 1024*2048/4
#define CVT_TOT (CVT_N0+CVT_N1+CVT_N2+CVT_N3+CVT_N4)

__global__ void cvt_all_kernel(const float* __restrict__ x,  u16* __restrict__ x_bf,
                               u8* __restrict__ x_f8,
                               const float* __restrict__ w1, u8* __restrict__ w1u_f8,
                               u16* __restrict__ w1r_bf,
                               const float* __restrict__ w2, u8* __restrict__ w2_f8,
                               const float* __restrict__ w3, u8* __restrict__ w3_f8) {
  const int stride = gridDim.x * blockDim.x;
  for (int i = blockIdx.x * blockDim.x + threadIdx.x; i < CVT_TOT; i += stride) {
    int j = i;
    if (j < CVT_N0) {
      f32x4 v = *(const f32x4*)(x + (size_t)j * 4);
      ushort4 o;
      o.x = f2bf(v.x); o.y = f2bf(v.y); o.z = f2bf(v.z); o.w = f2bf(v.w);
      *(ushort4*)(x_bf + (size_t)j * 4) = o;
      int p = 0;
      p = pk_fp8<false>(v.x * 16.f, v.y * 16.f, p);
      p = pk_fp8<true >(v.z * 16.f, v.w * 16.f, p);
      *(int*)(x_f8 + (size_t)j * 4) = p;
    } else if ((j -= CVT_N0) < CVT_N1) {
      f32x4 v = *(const f32x4*)(w1 + (size_t)j * 4);
      int p = 0;
      p = pk_fp8<false>(v.x * 16.f, v.y * 16.f, p);
      p = pk_fp8<true >(v.z * 16.f, v.w * 16.f, p);
      *(int*)(w1u_f8 + (size_t)j * 4) = p;
    } else if ((j -= CVT_N1) < CVT_N2) {
      f32x4 v = *(const f32x4*)(w1 + (size_t)(D_INNER * D_MODEL / 4 + j) * 4);
      ushort4 o;
      o.x = f2bf(v.x); o.y = f2bf(v.y); o.z = f2bf(v.z); o.w = f2bf(v.w);
      *(ushort4*)(w1r_bf + (size_t)j * 4) = o;
    } else if ((j -= CVT_N2) < CVT_N3) {
      f32x4 v = *(const f32x4*)(w2 + (size_t)j * 4);
      int p = 0;
      p = pk_fp8<false>(v.x * 16.f, v.y * 16.f, p);
      p = pk_fp8<true >(v.z * 16.f, v.w * 16.f, p);
      *(int*)(w2_f8 + (size_t)j * 4) = p;
    } else {
      j -= CVT_N3;
      f32x4 v = *(const f32x4*)(w3 + (size_t)j * 4);
      int p = 0;
      p = pk_fp8<false>(v.x * 16.f, v.y * 16.f, p);
      p = pk_fp8<true >(v.z * 16.f, v.w * 16.f, p);
      *(int*)(w3_f8 + (size_t)j * 4) = p;
    }
  }
}

// ---------------- 256x256 bf16 GEMM (res only): C = A @ B^T -> bf16 ---------
// R4 structure: quad-buffered LDS (BK=32), register-pipelined fragments,
// one s_barrier + counted vmcnt(4) per K-tile, T2 swizzle both-sides.
template<int K, int NBX>
__global__ __launch_bounds__(512, 2) void gemm256res(
    const u16* __restrict__ A, const u16* __restrict__ B,
    u16* __restrict__ out0)
{
  extern __shared__ char smem[];
  constexpr int NT = K / 32;
  const int tid  = threadIdx.x;
  const int lane = tid & 63;
  const int wave = tid >> 6;
  const int wm = wave >> 2, wn = wave & 3;

  const int nb  = (M_TOT / 256) * NBX;
  const int cpx = nb >> 3;
  const int wg  = ((int)blockIdx.x & 7) * cpx + ((int)blockIdx.x >> 3);
  const int m0 = (wg / NBX) << 8;
  const int n0 = (wg % NBX) << 8;

  const int st_row = (wave << 4) + (lane >> 2);
  const int st_kc  = (((lane & 3) ^ ((lane >> 3) & 3)) << 3);
  const u16* pA0 = A + (size_t)(m0 + st_row) * K + st_kc;
  const u16* pA1 = pA0 + (size_t)128 * K;
  const u16* pB0 = B + (size_t)(n0 + st_row) * K + st_kc;
  const u16* pB1 = pB0 + (size_t)128 * K;
  const int st_lds = wave << 10;

  const int l15 = lane & 15, k16 = lane >> 4;
  const int chunk = ((k16 ^ ((l15 >> 1) & 3)) << 4);
  const int aoff = (((wm << 7) + l15) << 6) + chunk;
  const int boff = (((wn << 6) + l15) << 6) + chunk;

  f32x4 acc[8][4] = {};
  bf16x8 fa0[8], fb0[4], fa1[8], fb1[4];

#define STAGE(ts_) do {                                   \
    char* ab_ = smem + (((ts_) & 3) << 14);               \
    char* bb_ = smem + 65536 + (((ts_) & 3) << 14);       \
    const int kt_ = (ts_) << 5;                           \
    g2l16(pA0 + kt_, ab_ + st_lds);                       \
    g2l16(pA1 + kt_, ab_ + 8192 + st_lds);                \
    g2l16(pB0 + kt_, bb_ + st_lds);                       \
    g2l16(pB1 + kt_, bb_ + 8192 + st_lds);                \
  } while (0)

#define READF(tr_, RA_, RB_) do {                                   \
    const char* Ab_ = smem + (((tr_) & 3) << 14);                   \
    const char* Bb_ = smem + 65536 + (((tr_) & 3) << 14);           \
    _Pragma("unroll")                                               \
    for (int i_ = 0; i_ < 8; ++i_)                                  \
      RA_[i_] = *(const bf16x8*)(Ab_ + aoff + (i_ << 10));          \
    _Pragma("unroll")                                               \
    for (int j_ = 0; j_ < 4; ++j_)                                  \
      RB_[j_] = *(const bf16x8*)(Bb_ + boff + (j_ << 10));          \
  } while (0)

#define ONE_ITER(t_, RA_, RB_, MA_, MB_) do {                        \
    if ((t_) + 1 < NT) {                                             \
      if ((t_) + 2 < NT) asm volatile("s_waitcnt vmcnt(4)" ::: "memory"); \
      else               asm volatile("s_waitcnt vmcnt(0)" ::: "memory"); \
      __builtin_amdgcn_s_barrier();                                  \
      __builtin_amdgcn_sched_barrier(0);                             \
      READF((t_) + 1, RA_, RB_);                                     \
    }                                                                \
    if ((t_) + 3 < NT) STAGE((t_) + 3);                              \
    __builtin_amdgcn_sched_barrier(0);                               \
    __builtin_amdgcn_s_setprio(1);                                   \
    _Pragma("unroll")                                                \
    for (int j_ = 0; j_ < 4; ++j_) {                                 \
      _Pragma("unroll")                                              \
      for (int i_ = 0; i_ < 8; ++i_)                                 \
        acc[i_][j_] = __builtin_amdgcn_mfma_f32_16x16x32_bf16(MA_[i_], MB_[j_], acc[i_][j_], 0, 0, 0); \
    }                                                                \
    __builtin_amdgcn_s_setprio(0);                                   \
    __builtin_amdgcn_sched_barrier(0);                               \
  } while (0)

  #pragma unroll
  for (int pt = 0; pt < 3; ++pt) STAGE(pt);
  asm volatile("s_waitcnt vmcnt(8)" ::: "memory");
  __builtin_amdgcn_s_barrier();
  __builtin_amdgcn_sched_barrier(0);
  READF(0, fa0, fb0);

  for (int t = 0; t < NT; t += 2) {
    ONE_ITER(t,     fa1, fb1, fa0, fb0);
    ONE_ITER(t + 1, fa0, fb0, fa1, fb1);
  }
#undef STAGE
#undef READF
#undef ONE_ITER

  // epilogue: C/D 16x16 layout col=lane&15, row=(lane>>4)*4+reg [verified r1-12]
  __syncthreads();
  float (*sc)[260] = (float(*)[260])smem;
  const int lr = (lane >> 4) << 2;
  const int lc = lane & 15;
  #pragma unroll
  for (int p = 0; p < 4; ++p) {
    if (wm == (p >> 1)) {
      const int ib = (p & 1) << 2;
      #pragma unroll
      for (int ii = 0; ii < 4; ++ii)
        #pragma unroll
        for (int j = 0; j < 4; ++j)
          #pragma unroll
          for (int r = 0; r < 4; ++r)
            sc[(ii << 4) + lr + r][(wn << 6) + (j << 4) + lc] = acc[ib + ii][j][r];
    }
    __syncthreads();
    #pragma unroll
    for (int rr = 0; rr < 8; ++rr) {
      const int row = (rr << 3) + wave;
      const int col = (tid & 63) << 2;
      const f32x4 v = *(const f32x4*)&sc[row][col];
      const int gr = m0 + (p << 6) + row;
      const int gc = n0 + col;
      ushort4 o;
      o.x = f2bf(v.x); o.y = f2bf(v.y); o.z = f2bf(v.z); o.w = f2bf(v.w);
      *(ushort4*)&out0[(size_t)gr * N_RES + gc] = o;
    }
    __syncthreads();
  }
}

// ---------------- 256x256 MX-fp8 GEMM, C = A @ B^T  (BK=64, 32x32x64) -------
// R12 structure (verified): quad-buffer LDS, single-buf fragments, counted
// vmcnt, unit e8m0 scales. C/D 32x32: col=lane&31, row=(reg&3)+8*(reg>>2)+
// 4*(lane>>5). EPI 0: u = acc/256, store fp8 x64 (= acc*0.25), stride D_INNER.
// EPI 1: d=acc/1024+bias; gated_raw = uc_raw * sigmoid(softplus(d)) -> fp8.
// EPI 2: out f32 = acc/1024 + res(bf16), stride N_RES.
template<int EPI, int K, int NBX>
__global__ __launch_bounds__(512, 2) void gemm256mx(
    const u8* __restrict__ A, const u8* __restrict__ B,
    void* __restrict__ out0, void* __restrict__ out1,
    const float* __restrict__ bias)
{
  extern __shared__ char smem[];
  constexpr int NT = K / 64;
  const int tid  = threadIdx.x;
  const int lane = tid & 63;
  const int wave = tid >> 6;
  const int wm = wave >> 2, wn = wave & 3;

  const int nb  = (M_TOT / 256) * NBX;
  const int cpx = nb >> 3;
  const int wg  = ((int)blockIdx.x & 7) * cpx + ((int)blockIdx.x >> 3);
  const int m0 = (wg / NBX) << 8;
  const int n0 = (wg % NBX) << 8;

  const int st_row = (wave << 4) + (lane >> 2);
  const int st_kc  = (((lane & 3) ^ ((lane >> 3) & 3)) << 4);
  const u8* pA0 = A + (size_t)(m0 + st_row) * K + st_kc;
  const u8* pA1 = pA0 + (size_t)128 * K;
  const u8* pB0 = B + (size_t)(n0 + st_row) * K + st_kc;
  const u8* pB1 = pB0 + (size_t)128 * K;
  const int st_lds = wave << 10;

  const int l31 = lane & 31;
  const int x2  = (l31 >> 1) & 3;
  const int c0  = (lane >> 5) << 1;
  const int slot0 = ((c0     ^ x2) << 4);
  const int slot1 = (((c0+1) ^ x2) << 4);
  const int abase = ((wm << 7) + l31) << 6;
  const int bbase = ((wn << 6) + l31) << 6;

  f32x16 acc[4][2] = {};
  i32x8 fa[4], fb[2];

#define STAGE(ts_) do {                                   \
    char* ab_ = smem + (((ts_) & 3) << 14);               \
    char* bb_ = smem + 65536 + (((ts_) & 3) << 14);       \
    const int kt_ = (ts_) << 6;                           \
    g2l16(pA0 + kt_, ab_ + st_lds);                       \
    g2l16(pA1 + kt_, ab_ + 8192 + st_lds);                \
    g2l16(pB0 + kt_, bb_ + st_lds);                       \
    g2l16(pB1 + kt_, bb_ + 8192 + st_lds);                \
  } while (0)

#define READF(tr_) do {                                               \
    const char* Ab_ = smem + (((tr_) & 3) << 14);                     \
    const char* Bb_ = smem + 65536 + (((tr_) & 3) << 14);             \
    _Pragma("unroll")                                                 \
    for (int i_ = 0; i_ < 4; ++i_) {                                  \
      const char* p_ = Ab_ + abase + (i_ << 11);                      \
      i32x4v lo_ = *(const i32x4v*)(p_ + slot0);                      \
      i32x4v hi_ = *(const i32x4v*)(p_ + slot1);                      \
      i32x8 v_;                                                       \
      v_[0]=lo_[0]; v_[1]=lo_[1]; v_[2]=lo_[2]; v_[3]=lo_[3];         \
      v_[4]=hi_[0]; v_[5]=hi_[1]; v_[6]=hi_[2]; v_[7]=hi_[3];         \
      fa[i_] = v_;                                                    \
    }                                                                 \
    _Pragma("unroll")                                                 \
    for (int j_ = 0; j_ < 2; ++j_) {                                  \
      const char* p_ = Bb_ + bbase + (j_ << 11);                      \
      i32x4v lo_ = *(const i32x4v*)(p_ + slot0);                      \
      i32x4v hi_ = *(const i32x4v*)(p_ + slot1);                      \
      i32x8 v_;                                                       \
      v_[0]=lo_[0]; v_[1]=lo_[1]; v_[2]=lo_[2]; v_[3]=lo_[3];         \
      v_[4]=hi_[0]; v_[5]=hi_[1]; v_[6]=hi_[2]; v_[7]=hi_[3];         \
      fb[j_] = v_;                                                    \
    }                                                                 \
  } while (0)

  #pragma unroll
  for (int pt = 0; pt < 3; ++pt) STAGE(pt);

  for (int t = 0; t < NT; ++t) {
    if (t + 2 < NT)      asm volatile("s_waitcnt vmcnt(8)" ::: "memory");
    else if (t + 1 < NT) asm volatile("s_waitcnt vmcnt(4)" ::: "memory");
    else                 asm volatile("s_waitcnt vmcnt(0)" ::: "memory");
    __builtin_amdgcn_s_barrier();
    __builtin_amdgcn_sched_barrier(0);
    READF(t);
    if (t + 3 < NT) STAGE(t + 3);
    __builtin_amdgcn_sched_barrier(0);
    __builtin_amdgcn_s_setprio(1);
    #pragma unroll
    for (int j_ = 0; j_ < 2; ++j_) {
      #pragma unroll
      for (int i_ = 0; i_ < 4; ++i_)
        acc[i_][j_] = __builtin_amdgcn_mfma_scale_f32_32x32x64_f8f6f4(
            fa[i_], fb[j_], acc[i_][j_], 0, 0,
            0, 0x7F7F7F7F, 0, 0x7F7F7F7F);   // unit e8m0 scales
    }
    __builtin_amdgcn_s_setprio(0);
    __builtin_amdgcn_sched_barrier(0);
  }
#undef STAGE
#undef READF

  // epilogue; C/D 32x32 layout
  __syncthreads();
  float (*sc)[260] = (float(*)[260])smem;
  const int r32b = ((lane >> 5) << 2);
  #pragma unroll
  for (int p = 0; p < 4; ++p) {
    if (wm == (p >> 1)) {
      #pragma unroll
      for (int it = 0; it < 2; ++it) {
        const int i_ = ((p & 1) << 1) + it;
        #pragma unroll
        for (int j = 0; j < 2; ++j)
          #pragma unroll
          for (int r = 0; r < 16; ++r) {
            const int r32 = (r & 3) + ((r >> 2) << 3) + r32b;
            sc[(it << 5) + r32][(wn << 6) + (j << 5) + l31] = acc[i_][j][r];
          }
      }
    }
    __syncthreads();
    #pragma unroll
    for (int rr = 0; rr < 8; ++rr) {
      const int row = (rr << 3) + wave;
      const int col = (tid & 63) << 2;
      const f32x4 v = *(const f32x4*)&sc[row][col];
      const int gr = m0 + (p << 6) + row;
      const int gc = n0 + col;
      if constexpr (EPI == 0) {
        // u = acc/256 ; store u*64 = acc*0.25 as fp8
        int pk = 0;
        pk = pk_fp8<false>(v.x * 0.25f, v.y * 0.25f, pk);
        pk = pk_fp8<true >(v.z * 0.25f, v.w * 0.25f, pk);
        *(int*)&((u8*)out0)[(size_t)gr * D_INNER + gc] = pk;
      } else if constexpr (EPI == 1) {
        const f32x4 b4 = *(const f32x4*)&bias[gc];
        const int uw = *(const int*)&((const u8*)out1)[(size_t)gr * D_INNER + gc];
        const float ucr[4] = { up_fp8<0>(uw), up_fp8<1>(uw), up_fp8<2>(uw), up_fp8<3>(uw) };
        float vv[4] = {v.x, v.y, v.z, v.w};
        float bb[4] = {b4.x, b4.y, b4.z, b4.w};
        float gg[4];
        #pragma unroll
        for (int q = 0; q < 4; ++q) {
          const float d  = vv[q] * 0.0009765625f + bb[q];
          const float sp = (d > 15.f) ? d : __logf(1.f + __expf(d));
          const float sg = 1.f / (1.f + __expf(-sp));
          gg[q] = ucr[q] * sg;            // raw = 64*gated
        }
        int pk = 0;
        pk = pk_fp8<false>(gg[0], gg[1], pk);
        pk = pk_fp8<true >(gg[2], gg[3], pk);
        *(int*)&((u8*)out0)[(size_t)gr * D_INNER + gc] = pk;
      } else {
        const ushort4 rv = *(const ushort4*)&((const u16*)out1)[(size_t)gr * N_RES + gc];
        f32x4 o;
        o.x = v.x * 0.0009765625f + bf2f(rv.x);
        o.y = v.y * 0.0009765625f + bf2f(rv.y);
        o.z = v.z * 0.0009765625f + bf2f(rv.z);
        o.w = v.w * 0.0009765625f + bf2f(rv.w);
        *(f32x4*)&((float*)out0)[(size_t)gr * N_RES + gc] = o;
      }
    }
    __syncthreads();
  }
}

// ---------------- depthwise causal conv (4 taps), fp8 in (x64) -> fp8 out ---
__global__ __launch_bounds__(256) void conv_kernel(
    const u8* __restrict__ u, u8* __restrict__ uc,
    const float* __restrict__ cw, const float* __restrict__ cb)
{
  const int c0 = threadIdx.x * 8;
  const int b  = blockIdx.x >> 8;
  const int t0 = (blockIdx.x & 255) << 4;
  const size_t base = (size_t)b * SEQ * D_INNER;

  float w0[8], w1[8], w2[8], w3[8], bs[8];
  #pragma unroll
  for (int j = 0; j < 8; ++j) {
    const float* wp = cw + (size_t)(c0 + j) * 4;
    w0[j] = wp[0]; w1[j] = wp[1]; w2[j] = wp[2]; w3[j] = wp[3];
    bs[j] = cb[c0 + j] * 64.f;          // work in x64 domain
  }

  float r0[8], r1[8], r2[8];
  #pragma unroll
  for (int k = 0; k < 3; ++k) {
    const int t = t0 - 3 + k;
    float* rr = (k == 0) ? r0 : (k == 1) ? r1 : r2;
    if (t >= 0) {
      int2 v = *(const int2*)&u[base + (size_t)t * D_INNER + c0];
      rr[0] = up_fp8<0>(v.x); rr[1] = up_fp8<1>(v.x);
      rr[2] = up_fp8<2>(v.x); rr[3] = up_fp8<3>(v.x);
      rr[4] = up_fp8<0>(v.y); rr[5] = up_fp8<1>(v.y);
      rr[6] = up_fp8<2>(v.y); rr[7] = up_fp8<3>(v.y);
    } else {
      #pragma unroll
      for (int j = 0; j < 8; ++j) rr[j] = 0.f;
    }
  }

  #pragma unroll
  for (int tt = 0; tt < 16; ++tt) {
    const size_t off = base + (size_t)(t0 + tt) * D_INNER + c0;
    int2 v = *(const int2*)&u[off];
    float cur[8], s[8];
    cur[0] = up_fp8<0>(v.x); cur[1] = up_fp8<1>(v.x);
    cur[2] = up_fp8<2>(v.x); cur[3] = up_fp8<3>(v.x);
    cur[4] = up_fp8<0>(v.y); cur[5] = up_fp8<1>(v.y);
    cur[6] = up_fp8<2>(v.y); cur[7] = up_fp8<3>(v.y);
    #pragma unroll
    for (int j = 0; j < 8; ++j)
      s[j] = bs[j] + w0[j]*r0[j] + w1[j]*r1[j] + w2[j]*r2[j] + w3[j]*cur[j];
    int p0 = 0, p1 = 0;
    p0 = pk_fp8<false>(s[0], s[1], p0); p0 = pk_fp8<true>(s[2], s[3], p0);
    p1 = pk_fp8<false>(s[4], s[5], p1); p1 = pk_fp8<true>(s[6], s[7], p1);
    int2 o; o.x = p0; o.y = p1;
    *(int2*)&uc[off] = o;
    #pragma unroll
    for (int j = 0; j < 8; ++j) { r0[j] = r1[j]; r1[j] = r2[j]; r2[j] = cur[j]; }
  }
}

// ---------------- chunked IIR scan, fp8 in (x64) -> fp8 out (x64) -----------
// chunk=128, warm-up=96 (0.9^96 ~ 4e-5); state kept in x64 domain
__global__ __launch_bounds__(256) void scan_kernel(const u8* __restrict__ g, u8* __restrict__ y) {
  const int cg    = blockIdx.x & 1;
  const int chunk = (blockIdx.x >> 1) & 31;
  const int b     = blockIdx.x >> 6;
  const int c0 = cg * 1024 + threadIdx.x * 4;
  const int t0 = chunk << 7;
  const size_t base = (size_t)b * SEQ * D_INNER + c0;
  float s0 = 0.f, s1 = 0.f, s2 = 0.f, s3 = 0.f;
  const int tw = (t0 >= 96) ? t0 - 96 : 0;
  for (int t = tw; t < t0; ++t) {
    const int v = *(const int*)&g[base + (size_t)t * D_INNER];
    s0 = s0*0.9f + up_fp8<0>(v)*0.1f; s1 = s1*0.9f + up_fp8<1>(v)*0.1f;
    s2 = s2*0.9f + up_fp8<2>(v)*0.1f; s3 = s3*0.9f + up_fp8<3>(v)*0.1f;
  }
  for (int t = t0; t < t0 + 128; ++t) {
    const int v = *(const int*)&g[base + (size_t)t * D_INNER];
    s0 = s0*0.9f + up_fp8<0>(v)*0.1f; s1 = s1*0.9f + up_fp8<1>(v)*0.1f;
    s2 = s2*0.9f + up_fp8<2>(v)*0.1f; s3 = s3*0.9f + up_fp8<3>(v)*0.1f;
    int p = 0;
    p = pk_fp8<false>(s0, s1, p);
    p = pk_fp8<true >(s2, s3, p);
    *(int*)&y[base + (size_t)t * D_INNER] = p;
  }
}

extern "C" void kernel_launch(void* const* d_in, const int* in_sizes, int n_in,
                              void* d_out, int out_size, void* d_ws, size_t ws_size,
                              hipStream_t stream) {
  (void)in_sizes; (void)n_in; (void)out_size; (void)ws_size;
  const float* x  = (const float*)d_in[0];
  const float* w1 = (const float*)d_in[1];   // in_proj_w (3072,1024)
  const float* cw = (const float*)d_in[2];   // conv_w (2048,1,4)
  const float* cb = (const float*)d_in[3];   // conv_b (2048,)
  const float* w2 = (const float*)d_in[5];   // dt_proj_w (2048,2048)
  const float* db = (const float*)d_in[6];   // dt_proj_b (2048,)
  const float* w3 = (const float*)d_in[9];   // out_proj_w (1024,2048)
  // d_in[4]=x_proj_w, d_in[7]=A_log, d_in[8]=D are dead in the reference.

  char* ws = (char*)d_ws;
  u16* x_bf    = (u16*)(ws);                  // 33,554,432  [gated_f8 aliases after GEMM1res]
  u8*  x_f8    = (u8*) (ws + 33554432);       // 16,777,216
  u8*  w1u_f8  = (u8*) (ws + 50331648);       //  2,097,152
  u16* w1r_bf  = (u16*)(ws + 52428800);       //  2,097,152
  u8*  w2_f8   = (u8*) (ws + 54525952);       //  4,194,304
  u8*  w3_f8   = (u8*) (ws + 58720256);       //  2,097,152
  u8*  u_f8    = (u8*) (ws + 60817408);       // 33,554,432  [y_f8 aliases after conv]
  u16* res_bf  = (u16*)(ws + 94371840);       // 33,554,432
  u8*  uc_f8   = (u8*) (ws + 127926272);      // 33,554,432  (total ~154 MB)
  u8*  gated_f8 = (u8*)(ws);                  // alias of x_bf (dead after GEMM1res)
  u8*  y_f8    = u_f8;                        // alias of u_f8 (dead after conv)

  (void)hipFuncSetAttribute((const void*)&gemm256res<1024,4>,   hipFuncAttributeMaxDynamicSharedMemorySize, SMEM_BYTES);
  (void)hipFuncSetAttribute((const void*)&gemm256mx<0,1024,8>,  hipFuncAttributeMaxDynamicSharedMemorySize, SMEM_BYTES);
  (void)hipFuncSetAttribute((const void*)&gemm256mx<1,2048,8>,  hipFuncAttributeMaxDynamicSharedMemorySize, SMEM_BYTES);
  (void)hipFuncSetAttribute((const void*)&gemm256mx<2,2048,4>,  hipFuncAttributeMaxDynamicSharedMemorySize, SMEM_BYTES);

  // all conversions in one launch
  cvt_all_kernel<<<2048, 256, 0, stream>>>(x, x_bf, x_f8, w1, w1u_f8, w1r_bf,
                                           w2, w2_f8, w3, w3_f8);

  // GEMM1u (MX-fp8): (16384x1024)@(1024x2048)^T -> u_f8 (x64)
  gemm256mx<0, 1024, 8><<<512, 512, SMEM_BYTES, stream>>>(x_f8, w1u_f8, u_f8, nullptr, nullptr);
  // GEMM1res (bf16): (16384x1024)@(1024x1024)^T -> res_bf
  gemm256res<1024, 4><<<256, 512, SMEM_BYTES, stream>>>(x_bf, w1r_bf, res_bf);
  // depthwise causal conv (fp8 -> fp8, x64 domain)
  conv_kernel<<<1024, 256, 0, stream>>>(u_f8, uc_f8, cw, cb);
  // GEMM2 (MX-fp8) + bias + softplus + sigmoid + gate -> gated_f8 (x64)
  gemm256mx<1, 2048, 8><<<512, 512, SMEM_BYTES, stream>>>(uc_f8, w2_f8, gated_f8, uc_f8, db);
  // chunked scan (fp8 -> fp8, x64 domain)
  scan_kernel<<<256, 256, 0, stream>>>(gated_f8, y_f8);
  // GEMM3 (MX-fp8) + res add -> d_out (f32)
  gemm256mx<2, 2048, 4><<<256, 512, SMEM_BYTES, stream>>>(y_f8, w3_f8, d_out, res_bf, nullptr);
}

// Round 15
// 314.693 us; speedup vs baseline: 1.0658x; 1.0658x over previous
//
#include <hip/hip_runtime.h>
#include <stdint.h>
#include <math.h>

#define D_MODEL 1024
#define D_INNER 2048
#define N_RES   1024
#define SEQ     4096
#define BATCH   4
#define M_TOT   (BATCH*SEQ)   // 16384
#define SMEM_BYTES 131072

typedef float f32x4 __attribute__((ext_vector_type(4)));
typedef float f32x16 __attribute__((ext_vector_type(16)));
typedef short bf16x8 __attribute__((ext_vector_type(8)));
typedef int   i32x4v __attribute__((ext_vector_type(4)));
typedef int   i32x8  __attribute__((ext_vector_type(8)));
typedef unsigned short u16;
typedef unsigned char u8;

__device__ __forceinline__ u16 f2bf(float f) {
  uint32_t u = __builtin_bit_cast(uint32_t, f);
  u += 0x7FFFu + ((u >> 16) & 1u);   // RNE
  return (u16)(u >> 16);
}
__device__ __forceinline__ float bf2f(u16 h) {
  return __builtin_bit_cast(float, (uint32_t)h << 16);
}

// ---- fp8 e4m3fn (OCP) encode/decode; builtin ICE operands via template ----
__device__ __forceinline__ uint32_t enc1_e4m3(float f) {
  uint32_t b = __builtin_bit_cast(uint32_t, f);
  uint32_t s = (b >> 24) & 0x80u;
  uint32_t a = b & 0x7FFFFFFFu;
  if (a >= 0x43E00000u) return s | 0x7Eu;            // >=448 or NaN -> sat
  if (a < 0x3C800000u) {                             // < 2^-6 -> subnormal
    float q = __builtin_bit_cast(float, a) * 512.f;
    uint32_t m = (uint32_t)(q + 0.5f);
    return s | (m > 7u ? 8u : m);
  }
  uint32_t lsb = (a >> 20) & 1u;
  a += 0x0007FFFFu + lsb;                            // RNE at mantissa bit 20
  uint32_t e8 = (a >> 23) - 120u;
  if (e8 >= 16u) return s | 0x7Eu;
  return s | (e8 << 3) | ((a >> 20) & 7u);
}
__device__ __forceinline__ float dec1_e4m3(uint32_t v) {
  uint32_t e = (v >> 3) & 15u, m = v & 7u;
  float mag = e ? __builtin_bit_cast(float, ((e + 120u) << 23) | (m << 20))
                : (float)m * 0.001953125f;
  return (v & 0x80u) ? -mag : mag;
}
template<bool HI>
__device__ __forceinline__ int pk_fp8(float a, float b, int old) {
#if __has_builtin(__builtin_amdgcn_cvt_pk_fp8_f32)
  return __builtin_amdgcn_cvt_pk_fp8_f32(a, b, old, HI);
#else
  uint32_t w = enc1_e4m3(a) | (enc1_e4m3(b) << 8);
  return HI ? (int)(((uint32_t)old & 0xFFFFu) | (w << 16))
            : (int)(((uint32_t)old & 0xFFFF0000u) | w);
#endif
}
template<int SEL>
__device__ __forceinline__ float up_fp8(int w) {
#if __has_builtin(__builtin_amdgcn_cvt_f32_fp8)
  return __builtin_amdgcn_cvt_f32_fp8(w, SEL);
#else
  return dec1_e4m3(((uint32_t)w >> (SEL * 8)) & 0xFFu);
#endif
}

__device__ __forceinline__ void g2l16(const void* g, void* l) {
  __builtin_amdgcn_global_load_lds(
      (const __attribute__((address_space(1))) void*)g,
      (__attribute__((address_space(3))) void*)l, 16, 0, 0);
}

// ---------------- fused convert (1 launch): x,w1 -> bf16 ; w2,w3 -> fp8*16 ----
#define CVT_N0 4194304   // x  : 16384*1024/4
#define CVT_N1  786432   // w1 : 3072*1024/4
#define CVT_N2 1048576   // w2 : 2048*2048/4
#define CVT_N3  524288   // w3 : 1024*2048/4
#define CVT_TOT (CVT_N0+CVT_N1+CVT_N2+CVT_N3)

__global__ void cvt_all_kernel(const float* __restrict__ s0, u16* __restrict__ d0,
                               const float* __restrict__ s1, u16* __restrict__ d1,
                               const float* __restrict__ s2, u8* __restrict__ d2,
                               const float* __restrict__ s3, u8* __restrict__ d3) {
  const int stride = gridDim.x * blockDim.x;
  for (int i = blockIdx.x * blockDim.x + threadIdx.x; i < CVT_TOT; i += stride) {
    int j = i;
    if (j < CVT_N0 + CVT_N1) {
      const float* src; u16* dst;
      if (j < CVT_N0) { src = s0; dst = d0; } else { j -= CVT_N0; src = s1; dst = d1; }
      f32x4 v = *(const f32x4*)(src + (size_t)j * 4);
      ushort4 o;
      o.x = f2bf(v.x); o.y = f2bf(v.y); o.z = f2bf(v.z); o.w = f2bf(v.w);
      *(ushort4*)(dst + (size_t)j * 4) = o;
    } else {
      j -= CVT_N0 + CVT_N1;
      const float* src; u8* dst;
      if (j < CVT_N2) { src = s2; dst = d2; } else { j -= CVT_N2; src = s3; dst = d3; }
      f32x4 v = *(const f32x4*)(src + (size_t)j * 4);
      int p = 0;
      p = pk_fp8<false>(v.x * 16.f, v.y * 16.f, p);
      p = pk_fp8<true >(v.z * 16.f, v.w * 16.f, p);
      *(int*)(dst + (size_t)j * 4) = p;
    }
  }
}

// ---------------- 256x256 bf16 GEMM1: C = A @ B^T -> u(fp8 x64) / res(bf16) -
// R4 structure: quad-buffered LDS (BK=32), register-pipelined fragments,
// one s_barrier + counted vmcnt(4) per K-tile, T2 swizzle both-sides.
template<int K, int NBX>
__global__ __launch_bounds__(512, 2) void gemm256bf(
    const u16* __restrict__ A, const u16* __restrict__ B,
    u8* __restrict__ out_u, u16* __restrict__ out_res)
{
  extern __shared__ char smem[];
  constexpr int NT = K / 32;
  const int tid  = threadIdx.x;
  const int lane = tid & 63;
  const int wave = tid >> 6;
  const int wm = wave >> 2, wn = wave & 3;

  const int nb  = (M_TOT / 256) * NBX;
  const int cpx = nb >> 3;
  const int wg  = ((int)blockIdx.x & 7) * cpx + ((int)blockIdx.x >> 3);
  const int m0 = (wg / NBX) << 8;
  const int n0 = (wg % NBX) << 8;

  const int st_row = (wave << 4) + (lane >> 2);
  const int st_kc  = (((lane & 3) ^ ((lane >> 3) & 3)) << 3);
  const u16* pA0 = A + (size_t)(m0 + st_row) * K + st_kc;
  const u16* pA1 = pA0 + (size_t)128 * K;
  const u16* pB0 = B + (size_t)(n0 + st_row) * K + st_kc;
  const u16* pB1 = pB0 + (size_t)128 * K;
  const int st_lds = wave << 10;

  const int l15 = lane & 15, k16 = lane >> 4;
  const int chunk = ((k16 ^ ((l15 >> 1) & 3)) << 4);
  const int aoff = (((wm << 7) + l15) << 6) + chunk;
  const int boff = (((wn << 6) + l15) << 6) + chunk;

  f32x4 acc[8][4] = {};
  bf16x8 fa0[8], fb0[4], fa1[8], fb1[4];

#define STAGE(ts_) do {                                   \
    char* ab_ = smem + (((ts_) & 3) << 14);               \
    char* bb_ = smem + 65536 + (((ts_) & 3) << 14);       \
    const int kt_ = (ts_) << 5;                           \
    g2l16(pA0 + kt_, ab_ + st_lds);                       \
    g2l16(pA1 + kt_, ab_ + 8192 + st_lds);                \
    g2l16(pB0 + kt_, bb_ + st_lds);                       \
    g2l16(pB1 + kt_, bb_ + 8192 + st_lds);                \
  } while (0)

#define READF(tr_, RA_, RB_) do {                                   \
    const char* Ab_ = smem + (((tr_) & 3) << 14);                   \
    const char* Bb_ = smem + 65536 + (((tr_) & 3) << 14);           \
    _Pragma("unroll")                                               \
    for (int i_ = 0; i_ < 8; ++i_)                                  \
      RA_[i_] = *(const bf16x8*)(Ab_ + aoff + (i_ << 10));          \
    _Pragma("unroll")                                               \
    for (int j_ = 0; j_ < 4; ++j_)                                  \
      RB_[j_] = *(const bf16x8*)(Bb_ + boff + (j_ << 10));          \
  } while (0)

#define ONE_ITER(t_, RA_, RB_, MA_, MB_) do {                        \
    if ((t_) + 1 < NT) {                                             \
      if ((t_) + 2 < NT) asm volatile("s_waitcnt vmcnt(4)" ::: "memory"); \
      else               asm volatile("s_waitcnt vmcnt(0)" ::: "memory"); \
      __builtin_amdgcn_s_barrier();                                  \
      __builtin_amdgcn_sched_barrier(0);                             \
      READF((t_) + 1, RA_, RB_);                                     \
    }                                                                \
    if ((t_) + 3 < NT) STAGE((t_) + 3);                              \
    __builtin_amdgcn_sched_barrier(0);                               \
    __builtin_amdgcn_s_setprio(1);                                   \
    _Pragma("unroll")                                                \
    for (int j_ = 0; j_ < 4; ++j_) {                                 \
      _Pragma("unroll")                                              \
      for (int i_ = 0; i_ < 8; ++i_)                                 \
        acc[i_][j_] = __builtin_amdgcn_mfma_f32_16x16x32_bf16(MA_[i_], MB_[j_], acc[i_][j_], 0, 0, 0); \
    }                                                                \
    __builtin_amdgcn_s_setprio(0);                                   \
    __builtin_amdgcn_sched_barrier(0);                               \
  } while (0)

  #pragma unroll
  for (int pt = 0; pt < 3; ++pt) STAGE(pt);
  asm volatile("s_waitcnt vmcnt(8)" ::: "memory");
  __builtin_amdgcn_s_barrier();
  __builtin_amdgcn_sched_barrier(0);
  READF(0, fa0, fb0);

  for (int t = 0; t < NT; t += 2) {
    ONE_ITER(t,     fa1, fb1, fa0, fb0);
    ONE_ITER(t + 1, fa0, fb0, fa1, fb1);
  }
#undef STAGE
#undef READF
#undef ONE_ITER

  // epilogue: C/D 16x16 layout col=lane&15, row=(lane>>4)*4+reg [verified r1-13]
  __syncthreads();
  float (*sc)[260] = (float(*)[260])smem;
  const int lr = (lane >> 4) << 2;
  const int lc = lane & 15;
  #pragma unroll
  for (int p = 0; p < 4; ++p) {
    if (wm == (p >> 1)) {
      const int ib = (p & 1) << 2;
      #pragma unroll
      for (int ii = 0; ii < 4; ++ii)
        #pragma unroll
        for (int j = 0; j < 4; ++j)
          #pragma unroll
          for (int r = 0; r < 4; ++r)
            sc[(ii << 4) + lr + r][(wn << 6) + (j << 4) + lc] = acc[ib + ii][j][r];
    }
    __syncthreads();
    #pragma unroll
    for (int rr = 0; rr < 8; ++rr) {
      const int row = (rr << 3) + wave;
      const int col = (tid & 63) << 2;
      const f32x4 v = *(const f32x4*)&sc[row][col];
      const int gr = m0 + (p << 6) + row;
      const int gc = n0 + col;
      if (n0 < D_INNER) {
        // u -> fp8 x64  (|u| ~ 0.6, x64 well below 448 sat)
        int pk = 0;
        pk = pk_fp8<false>(v.x * 64.f, v.y * 64.f, pk);
        pk = pk_fp8<true >(v.z * 64.f, v.w * 64.f, pk);
        *(int*)&out_u[(size_t)gr * D_INNER + gc] = pk;
      } else {
        ushort4 o;
        o.x = f2bf(v.x); o.y = f2bf(v.y); o.z = f2bf(v.z); o.w = f2bf(v.w);
        *(ushort4*)&out_res[(size_t)gr * N_RES + (gc - D_INNER)] = o;
      }
    }
    __syncthreads();
  }
}

// ---------------- 256x256 MX-fp8 GEMM, C = A @ B^T  (BK=64, 32x32x64) -------
// R12 structure (verified): quad-buffer LDS, single-buf fragments, counted
// vmcnt, unit e8m0 scales. C/D 32x32: col=lane&31, row=(reg&3)+8*(reg>>2)+
// 4*(lane>>5).
// EPI 1: d=acc/1024+bias; gated_raw = uc_raw * sigmoid(softplus(d)) -> fp8 x64.
// EPI 2: out f32 = acc/1024 + res(bf16), stride N_RES.
template<int EPI, int K, int NBX>
__global__ __launch_bounds__(512, 2) void gemm256mx(
    const u8* __restrict__ A, const u8* __restrict__ B,
    void* __restrict__ out0, void* __restrict__ out1,
    const float* __restrict__ bias)
{
  extern __shared__ char smem[];
  constexpr int NT = K / 64;
  const int tid  = threadIdx.x;
  const int lane = tid & 63;
  const int wave = tid >> 6;
  const int wm = wave >> 2, wn = wave & 3;

  const int nb  = (M_TOT / 256) * NBX;
  const int cpx = nb >> 3;
  const int wg  = ((int)blockIdx.x & 7) * cpx + ((int)blockIdx.x >> 3);
  const int m0 = (wg / NBX) << 8;
  const int n0 = (wg % NBX) << 8;

  const int st_row = (wave << 4) + (lane >> 2);
  const int st_kc  = (((lane & 3) ^ ((lane >> 3) & 3)) << 4);
  const u8* pA0 = A + (size_t)(m0 + st_row) * K + st_kc;
  const u8* pA1 = pA0 + (size_t)128 * K;
  const u8* pB0 = B + (size_t)(n0 + st_row) * K + st_kc;
  const u8* pB1 = pB0 + (size_t)128 * K;
  const int st_lds = wave << 10;

  const int l31 = lane & 31;
  const int x2  = (l31 >> 1) & 3;
  const int c0  = (lane >> 5) << 1;
  const int slot0 = ((c0     ^ x2) << 4);
  const int slot1 = (((c0+1) ^ x2) << 4);
  const int abase = ((wm << 7) + l31) << 6;
  const int bbase = ((wn << 6) + l31) << 6;

  f32x16 acc[4][2] = {};
  i32x8 fa[4], fb[2];

#define STAGE(ts_) do {                                   \
    char* ab_ = smem + (((ts_) & 3) << 14);               \
    char* bb_ = smem + 65536 + (((ts_) & 3) << 14);       \
    const int kt_ = (ts_) << 6;                           \
    g2l16(pA0 + kt_, ab_ + st_lds);                       \
    g2l16(pA1 + kt_, ab_ + 8192 + st_lds);                \
    g2l16(pB0 + kt_, bb_ + st_lds);                       \
    g2l16(pB1 + kt_, bb_ + 8192 + st_lds);                \
  } while (0)

#define READF(tr_) do {                                               \
    const char* Ab_ = smem + (((tr_) & 3) << 14);                     \
    const char* Bb_ = smem + 65536 + (((tr_) & 3) << 14);             \
    _Pragma("unroll")                                                 \
    for (int i_ = 0; i_ < 4; ++i_) {                                  \
      const char* p_ = Ab_ + abase + (i_ << 11);                      \
      i32x4v lo_ = *(const i32x4v*)(p_ + slot0);                      \
      i32x4v hi_ = *(const i32x4v*)(p_ + slot1);                      \
      i32x8 v_;                                                       \
      v_[0]=lo_[0]; v_[1]=lo_[1]; v_[2]=lo_[2]; v_[3]=lo_[3];         \
      v_[4]=hi_[0]; v_[5]=hi_[1]; v_[6]=hi_[2]; v_[7]=hi_[3];         \
      fa[i_] = v_;                                                    \
    }                                                                 \
    _Pragma("unroll")                                                 \
    for (int j_ = 0; j_ < 2; ++j_) {                                  \
      const char* p_ = Bb_ + bbase + (j_ << 11);                      \
      i32x4v lo_ = *(const i32x4v*)(p_ + slot0);                      \
      i32x4v hi_ = *(const i32x4v*)(p_ + slot1);                      \
      i32x8 v_;                                                       \
      v_[0]=lo_[0]; v_[1]=lo_[1]; v_[2]=lo_[2]; v_[3]=lo_[3];         \
      v_[4]=hi_[0]; v_[5]=hi_[1]; v_[6]=hi_[2]; v_[7]=hi_[3];         \
      fb[j_] = v_;                                                    \
    }                                                                 \
  } while (0)

  #pragma unroll
  for (int pt = 0; pt < 3; ++pt) STAGE(pt);

  for (int t = 0; t < NT; ++t) {
    if (t + 2 < NT)      asm volatile("s_waitcnt vmcnt(8)" ::: "memory");
    else if (t + 1 < NT) asm volatile("s_waitcnt vmcnt(4)" ::: "memory");
    else                 asm volatile("s_waitcnt vmcnt(0)" ::: "memory");
    __builtin_amdgcn_s_barrier();
    __builtin_amdgcn_sched_barrier(0);
    READF(t);
    if (t + 3 < NT) STAGE(t + 3);
    __builtin_amdgcn_sched_barrier(0);
    __builtin_amdgcn_s_setprio(1);
    #pragma unroll
    for (int j_ = 0; j_ < 2; ++j_) {
      #pragma unroll
      for (int i_ = 0; i_ < 4; ++i_)
        acc[i_][j_] = __builtin_amdgcn_mfma_scale_f32_32x32x64_f8f6f4(
            fa[i_], fb[j_], acc[i_][j_], 0, 0,
            0, 0x7F7F7F7F, 0, 0x7F7F7F7F);   // unit e8m0 scales
    }
    __builtin_amdgcn_s_setprio(0);
    __builtin_amdgcn_sched_barrier(0);
  }
#undef STAGE
#undef READF

  // epilogue; C/D 32x32 layout
  __syncthreads();
  float (*sc)[260] = (float(*)[260])smem;
  const int r32b = ((lane >> 5) << 2);
  #pragma unroll
  for (int p = 0; p < 4; ++p) {
    if (wm == (p >> 1)) {
      #pragma unroll
      for (int it = 0; it < 2; ++it) {
        const int i_ = ((p & 1) << 1) + it;
        #pragma unroll
        for (int j = 0; j < 2; ++j)
          #pragma unroll
          for (int r = 0; r < 16; ++r) {
            const int r32 = (r & 3) + ((r >> 2) << 3) + r32b;
            sc[(it << 5) + r32][(wn << 6) + (j << 5) + l31] = acc[i_][j][r];
          }
      }
    }
    __syncthreads();
    #pragma unroll
    for (int rr = 0; rr < 8; ++rr) {
      const int row = (rr << 3) + wave;
      const int col = (tid & 63) << 2;
      const f32x4 v = *(const f32x4*)&sc[row][col];
      const int gr = m0 + (p << 6) + row;
      const int gc = n0 + col;
      if constexpr (EPI == 1) {
        const f32x4 b4 = *(const f32x4*)&bias[gc];
        const int uw = *(const int*)&((const u8*)out1)[(size_t)gr * D_INNER + gc];
        const float ucr[4] = { up_fp8<0>(uw), up_fp8<1>(uw), up_fp8<2>(uw), up_fp8<3>(uw) };
        float vv[4] = {v.x, v.y, v.z, v.w};
        float bb[4] = {b4.x, b4.y, b4.z, b4.w};
        float gg[4];
        #pragma unroll
        for (int q = 0; q < 4; ++q) {
          const float d  = vv[q] * 0.0009765625f + bb[q];
          const float sp = (d > 15.f) ? d : __logf(1.f + __expf(d));
          const float sg = 1.f / (1.f + __expf(-sp));
          gg[q] = ucr[q] * sg;            // raw = 64*gated
        }
        int pk = 0;
        pk = pk_fp8<false>(gg[0], gg[1], pk);
        pk = pk_fp8<true >(gg[2], gg[3], pk);
        *(int*)&((u8*)out0)[(size_t)gr * D_INNER + gc] = pk;
      } else {
        const ushort4 rv = *(const ushort4*)&((const u16*)out1)[(size_t)gr * N_RES + gc];
        f32x4 o;
        o.x = v.x * 0.0009765625f + bf2f(rv.x);
        o.y = v.y * 0.0009765625f + bf2f(rv.y);
        o.z = v.z * 0.0009765625f + bf2f(rv.z);
        o.w = v.w * 0.0009765625f + bf2f(rv.w);
        *(f32x4*)&((float*)out0)[(size_t)gr * N_RES + gc] = o;
      }
    }
    __syncthreads();
  }
}

// ---------------- depthwise causal conv (4 taps), fp8 in (x64) -> fp8 out ---
__global__ __launch_bounds__(256) void conv_kernel(
    const u8* __restrict__ u, u8* __restrict__ uc,
    const float* __restrict__ cw, const float* __restrict__ cb)
{
  const int c0 = threadIdx.x * 8;
  const int b  = blockIdx.x >> 8;
  const int t0 = (blockIdx.x & 255) << 4;
  const size_t base = (size_t)b * SEQ * D_INNER;

  float w0[8], w1[8], w2[8], w3[8], bs[8];
  #pragma unroll
  for (int j = 0; j < 8; ++j) {
    const float* wp = cw + (size_t)(c0 + j) * 4;
    w0[j] = wp[0]; w1[j] = wp[1]; w2[j] = wp[2]; w3[j] = wp[3];
    bs[j] = cb[c0 + j] * 64.f;          // work in x64 domain
  }

  float r0[8], r1[8], r2[8];
  #pragma unroll
  for (int k = 0; k < 3; ++k) {
    const int t = t0 - 3 + k;
    float* rr = (k == 0) ? r0 : (k == 1) ? r1 : r2;
    if (t >= 0) {
      int2 v = *(const int2*)&u[base + (size_t)t * D_INNER + c0];
      rr[0] = up_fp8<0>(v.x); rr[1] = up_fp8<1>(v.x);
      rr[2] = up_fp8<2>(v.x); rr[3] = up_fp8<3>(v.x);
      rr[4] = up_fp8<0>(v.y); rr[5] = up_fp8<1>(v.y);
      rr[6] = up_fp8<2>(v.y); rr[7] = up_fp8<3>(v.y);
    } else {
      #pragma unroll
      for (int j = 0; j < 8; ++j) rr[j] = 0.f;
    }
  }

  #pragma unroll
  for (int tt = 0; tt < 16; ++tt) {
    const size_t off = base + (size_t)(t0 + tt) * D_INNER + c0;
    int2 v = *(const int2*)&u[off];
    float cur[8], s[8];
    cur[0] = up_fp8<0>(v.x); cur[1] = up_fp8<1>(v.x);
    cur[2] = up_fp8<2>(v.x); cur[3] = up_fp8<3>(v.x);
    cur[4] = up_fp8<0>(v.y); cur[5] = up_fp8<1>(v.y);
    cur[6] = up_fp8<2>(v.y); cur[7] = up_fp8<3>(v.y);
    #pragma unroll
    for (int j = 0; j < 8; ++j)
      s[j] = bs[j] + w0[j]*r0[j] + w1[j]*r1[j] + w2[j]*r2[j] + w3[j]*cur[j];
    int p0 = 0, p1 = 0;
    p0 = pk_fp8<false>(s[0], s[1], p0); p0 = pk_fp8<true>(s[2], s[3], p0);
    p1 = pk_fp8<false>(s[4], s[5], p1); p1 = pk_fp8<true>(s[6], s[7], p1);
    int2 o; o.x = p0; o.y = p1;
    *(int2*)&uc[off] = o;
    #pragma unroll
    for (int j = 0; j < 8; ++j) { r0[j] = r1[j]; r1[j] = r2[j]; r2[j] = cur[j]; }
  }
}

// ---------------- chunked IIR scan, fp8 in (x64) -> fp8 out (x64) -----------
// chunk=128, warm-up=96 (0.9^96 ~ 4e-5); state kept in x64 domain
__global__ __launch_bounds__(256) void scan_kernel(const u8* __restrict__ g, u8* __restrict__ y) {
  const int cg    = blockIdx.x & 1;
  const int chunk = (blockIdx.x >> 1) & 31;
  const int b     = blockIdx.x >> 6;
  const int c0 = cg * 1024 + threadIdx.x * 4;
  const int t0 = chunk << 7;
  const size_t base = (size_t)b * SEQ * D_INNER + c0;
  float s0 = 0.f, s1 = 0.f, s2 = 0.f, s3 = 0.f;
  const int tw = (t0 >= 96) ? t0 - 96 : 0;
  for (int t = tw; t < t0; ++t) {
    const int v = *(const int*)&g[base + (size_t)t * D_INNER];
    s0 = s0*0.9f + up_fp8<0>(v)*0.1f; s1 = s1*0.9f + up_fp8<1>(v)*0.1f;
    s2 = s2*0.9f + up_fp8<2>(v)*0.1f; s3 = s3*0.9f + up_fp8<3>(v)*0.1f;
  }
  for (int t = t0; t < t0 + 128; ++t) {
    const int v = *(const int*)&g[base + (size_t)t * D_INNER];
    s0 = s0*0.9f + up_fp8<0>(v)*0.1f; s1 = s1*0.9f + up_fp8<1>(v)*0.1f;
    s2 = s2*0.9f + up_fp8<2>(v)*0.1f; s3 = s3*0.9f + up_fp8<3>(v)*0.1f;
    int p = 0;
    p = pk_fp8<false>(s0, s1, p);
    p = pk_fp8<true >(s2, s3, p);
    *(int*)&y[base + (size_t)t * D_INNER] = p;
  }
}

extern "C" void kernel_launch(void* const* d_in, const int* in_sizes, int n_in,
                              void* d_out, int out_size, void* d_ws, size_t ws_size,
                              hipStream_t stream) {
  (void)in_sizes; (void)n_in; (void)out_size; (void)ws_size;
  const float* x  = (const float*)d_in[0];
  const float* w1 = (const float*)d_in[1];   // in_proj_w (3072,1024)
  const float* cw = (const float*)d_in[2];   // conv_w (2048,1,4)
  const float* cb = (const float*)d_in[3];   // conv_b (2048,)
  const float* w2 = (const float*)d_in[5];   // dt_proj_w (2048,2048)
  const float* db = (const float*)d_in[6];   // dt_proj_b (2048,)
  const float* w3 = (const float*)d_in[9];   // out_proj_w (1024,2048)
  // d_in[4]=x_proj_w, d_in[7]=A_log, d_in[8]=D are dead in the reference.

  char* ws = (char*)d_ws;
  // fp8 activation buffers are 16384*2048 = 33,554,432 BYTES each (1 B/elem).
  u16* x_bf    = (u16*)(ws);                  // 33,554,432
  u16* w1_bf   = (u16*)(ws + 33554432);       //  6,291,456
  u8*  w2_f8   = (u8*) (ws + 39845888);       //  4,194,304
  u8*  w3_f8   = (u8*) (ws + 44040192);       //  2,097,152
  u8*  u_f8    = (u8*) (ws + 46137344);       // 33,554,432
  u8*  uc_f8   = (u8*) (ws + 79691776);       // 33,554,432
  u8*  gated_f8= (u8*) (ws + 113246208);      // 33,554,432
  u8*  y_f8    = (u8*) (ws + 146800640);      // 33,554,432
  u16* res_bf  = (u16*)(ws + 180355072);      // 33,554,432  (total ~214 MB)

  (void)hipFuncSetAttribute((const void*)&gemm256bf<1024,12>,   hipFuncAttributeMaxDynamicSharedMemorySize, SMEM_BYTES);
  (void)hipFuncSetAttribute((const void*)&gemm256mx<1,2048,8>,  hipFuncAttributeMaxDynamicSharedMemorySize, SMEM_BYTES);
  (void)hipFuncSetAttribute((const void*)&gemm256mx<2,2048,4>,  hipFuncAttributeMaxDynamicSharedMemorySize, SMEM_BYTES);

  // all conversions in one launch
  cvt_all_kernel<<<2048, 256, 0, stream>>>(x, x_bf, w1, w1_bf, w2, w2_f8, w3, w3_f8);

  // GEMM1 (bf16): (16384x1024)@(1024x3072)^T -> u_f8 (x64) / res_bf
  gemm256bf<1024, 12><<<768, 512, SMEM_BYTES, stream>>>(x_bf, w1_bf, u_f8, res_bf);
  // depthwise causal conv (fp8 -> fp8, x64 domain)
  conv_kernel<<<1024, 256, 0, stream>>>(u_f8, uc_f8, cw, cb);
  // GEMM2 (MX-fp8) + bias + softplus + sigmoid + gate -> gated_f8 (x64)
  gemm256mx<1, 2048, 8><<<512, 512, SMEM_BYTES, stream>>>(uc_f8, w2_f8, gated_f8, uc_f8, db);
  // chunked scan (fp8 -> fp8, x64 domain)
  scan_kernel<<<256, 256, 0, stream>>>(gated_f8, y_f8);
  // GEMM3 (MX-fp8) + res add -> d_out (f32)
  gemm256mx<2, 2048, 4><<<256, 512, SMEM_BYTES, stream>>>(y_f8, w3_f8, d_out, res_bf, nullptr);
}